// Round 4
// baseline (233.275 us; speedup 1.0000x reference)
//
#include <hip/hip_runtime.h>
#include <cstdint>
#include <cstddef>

// Problem constants
#define BB 2
#define SS 2048
#define EE 1024
#define HH 16
#define DD 64

typedef __attribute__((ext_vector_type(8))) short short8;           // 16x16x32 A/B frag
typedef __attribute__((ext_vector_type(4))) short shortx4;          // 16x16x16 A/B frag
typedef __attribute__((ext_vector_type(8))) unsigned short ushort8; // 16B vector ld/st
typedef __attribute__((ext_vector_type(4))) unsigned short ush4;    // 8B vector st
typedef __attribute__((ext_vector_type(4))) float floatx4;          // MFMA C/D frag / float4

#define MFMA32(a, b, c) __builtin_amdgcn_mfma_f32_16x16x32_bf16((a), (b), (c), 0, 0, 0)
#define MFMA16(a, b, c) __builtin_amdgcn_mfma_f32_16x16x16bf16_1k((a), (b), (c), 0, 0, 0)

// 0.125 (1/sqrt(64)) * log2(e): folded into Q so attn can use exp2 directly.
#define QSCALE 0.18033688011112042f

// direct global->LDS async copy, 16B/lane; LDS dest = wave-uniform base + lane*16
#define G2L16(g, l)                                                        \
    __builtin_amdgcn_global_load_lds(                                      \
        (const __attribute__((address_space(1))) void*)(g),                \
        (__attribute__((address_space(3))) void*)(l), 16, 0, 0)

// float -> bf16 bits, round-to-nearest-even
__device__ __forceinline__ unsigned short f2bf(float f) {
    unsigned int u = __float_as_uint(f);
    u += 0x7fffu + ((u >> 16) & 1u);
    return (unsigned short)(u >> 16);
}

// pack two floats into bf16x2 (round-half-up): 2 adds + 1 v_perm
__device__ __forceinline__ unsigned int pkbf(float a, float b) {
    return __builtin_amdgcn_perm(__float_as_uint(b) + 0x8000u,
                                 __float_as_uint(a) + 0x8000u, 0x07060302u);
}

// ---------------------------------------------------------------------------
// fp32 -> bf16 bulk converter, all 6 tensors in one launch.
// grid (1024, 6): g 0..1 -> x,y (1024 blocks); g 2..5 -> W (256 blocks each).
// ---------------------------------------------------------------------------
__global__ __launch_bounds__(256) void k_cvt(
    const float* __restrict__ x, unsigned short* __restrict__ xb,
    const float* __restrict__ y, unsigned short* __restrict__ yb,
    const float* __restrict__ w0, unsigned short* __restrict__ d0,
    const float* __restrict__ w1, unsigned short* __restrict__ d1,
    const float* __restrict__ w2, unsigned short* __restrict__ d2,
    const float* __restrict__ w3, unsigned short* __restrict__ d3)
{
    const int g = blockIdx.y;
    if (g >= 2 && blockIdx.x >= 256) return;
    const float* s = (g == 0) ? x : (g == 1) ? y : (g == 2) ? w0
                   : (g == 3) ? w1 : (g == 4) ? w2 : w3;
    unsigned short* d = (g == 0) ? xb : (g == 1) ? yb : (g == 2) ? d0
                      : (g == 3) ? d1 : (g == 4) ? d2 : d3;
    const size_t i = ((size_t)blockIdx.x * 256 + threadIdx.x) * 16;
    floatx4 f0 = *(const floatx4*)(s + i);
    floatx4 f1 = *(const floatx4*)(s + i + 4);
    floatx4 f2 = *(const floatx4*)(s + i + 8);
    floatx4 f3 = *(const floatx4*)(s + i + 12);
    ushort8 o0, o1;
#pragma unroll
    for (int j = 0; j < 4; ++j) { o0[j] = f2bf(f0[j]); o0[j + 4] = f2bf(f1[j]); }
#pragma unroll
    for (int j = 0; j < 4; ++j) { o1[j] = f2bf(f2[j]); o1[j + 4] = f2bf(f3[j]); }
    *(ushort8*)(d + i) = o0;
    *(ushort8*)(d + i + 8) = o1;
}

// ---------------------------------------------------------------------------
// GEMM: C[M,N] = (A[M,K] * W[N,K]^T + bias[N]) * oscale, bf16 in, fp32 accum.
// v2 (R4): 2-phase double-buffer (T3-minimum). R3 analysis: the old
// stage -> vmcnt(0)+barrier -> compute schedule exposes the full G2L16
// round-trip every 32-K subtile; with K=1024 (16 iters) and 2-3 blocks/CU
// there is little cross-block hiding. Now: As0/Bs0 and As1/Bs1 are ping-pong
// buffers; each phase issues next-subtile G2L16s into buf[other], computes
// buf[cur] (8 ds_read_b128 + 16 MFMA32 of useful work between issue and the
// compiler's vmcnt(0) drain at the phase-end barrier), then barriers once.
// Hazards: RAW (stage(i) -> read(i+1)) and WAR (read(i) -> stage(i+1)) are
// both separated by the phase barrier (vmcnt+lgkmcnt drained there). The 4
// buffers are distinct __shared__ objects so alias analysis won't stall the
// current-buffer ds_reads on the in-flight G2L16s. Barrier count unchanged.
// OMODE: 0 = bf16 row-major [M][1024], 1 = bf16 V-transposed [b*1024+col][2048],
//        2 = fp32 row-major [M][1024].
// ---------------------------------------------------------------------------
template <int MT, int OMODE>
__device__ __forceinline__ void gemm_body(
    const unsigned short* __restrict__ A, const unsigned short* __restrict__ W,
    const float* __restrict__ bias, void* __restrict__ Cv, float oscale,
    int m0, int n0, unsigned short* As0, unsigned short* As1,
    unsigned short* Bs0, unsigned short* Bs1)
{
    constexpr int K = 1024, N = 1024, LDT = 32;
    constexpr int MFR = MT / 32;  // m-frags per wave (wave tile = MT/2 x 64)
    const int t = threadIdx.x;
    const int lane = t & 63, w = t >> 6;
    const int q = lane >> 4, c = lane & 15;
    const int wm = w & 1, wn = w >> 1;
    const int lr = lane >> 2, lc = (lane & 3) * 8;  // 16 rows x 64B per G2L16

    // A staging: wave w covers rows w*(MT/4) .. +(MT/4)-1, in 16-row instrs.
    const unsigned short* gA0 = A + (size_t)(m0 + w * (MT / 4) + lr) * K + lc;
    const unsigned short* gA1 = gA0 + 16 * K;  // MT==128 only
    const unsigned short* gB0 = W + (size_t)(n0 + w * 32 + lr) * K + lc;
    const unsigned short* gB1 = gB0 + 16 * K;
    unsigned short* lA0 = As0 + (w * (MT / 4)) * LDT;  // buf0 A dest
    unsigned short* lA1 = As1 + (w * (MT / 4)) * LDT;  // buf1 A dest
    unsigned short* lB0 = Bs0 + (w * 32) * LDT;
    unsigned short* lB1 = Bs1 + (w * 32) * LDT;

    floatx4 acc[MFR][4] = {};

    // compute one 32-K subtile from buffer (Ah,Bh)
    auto compute = [&](const unsigned short* Ah, const unsigned short* Bh) {
        short8 af[MFR], bfr[4];
#pragma unroll
        for (int mi = 0; mi < MFR; ++mi)
            af[mi] = *(const short8*)
                &Ah[(wm * (MFR * 16) + mi * 16 + c) * LDT + q * 8];
#pragma unroll
        for (int ni = 0; ni < 4; ++ni)
            bfr[ni] = *(const short8*)
                &Bh[(wn * 64 + ni * 16 + c) * LDT + q * 8];
#pragma unroll
        for (int mi = 0; mi < MFR; ++mi)
#pragma unroll
            for (int ni = 0; ni < 4; ++ni)
                acc[mi][ni] = MFMA32(af[mi], bfr[ni], acc[mi][ni]);
    };

    // prologue: k-subtile 0 -> buffer 0
    G2L16(gA0, lA0);
    if constexpr (MT == 128) G2L16(gA1, lA0 + 16 * LDT);
    G2L16(gB0, lB0);
    G2L16(gB1, lB0 + 16 * LDT);

    for (int kt = 0; kt < K; kt += 64) {
        // --- phase A: stage kt+32 -> buf1, compute buf0 (k=kt) ---
        __syncthreads();  // buf0 staged (compiler drains vmcnt here)
        {
            const int nk = kt + 32;  // kt <= 960 -> nk <= 992, in range
            G2L16(gA0 + nk, lA1);
            if constexpr (MT == 128) G2L16(gA1 + nk, lA1 + 16 * LDT);
            G2L16(gB0 + nk, lB1);
            G2L16(gB1 + nk, lB1 + 16 * LDT);
        }
        compute(As0, Bs0);
        // --- phase B: stage kt+64 -> buf0, compute buf1 (k=kt+32) ---
        __syncthreads();  // buf1 staged; buf0 reads of phase A complete
        {
            const int nk = (kt + 64) & (K - 1);  // wraps to 0 on last phase:
            G2L16(gA0 + nk, lA0);                // dead re-stage of tile 0,
            if constexpr (MT == 128) G2L16(gA1 + nk, lA0 + 16 * LDT);  // keeps
            G2L16(gB0 + nk, lB0);                // loads unconditional
            G2L16(gB1 + nk, lB0 + 16 * LDT);
        }
        compute(As1, Bs1);
    }

#pragma unroll
    for (int ni = 0; ni < 4; ++ni) {
        const int col = n0 + wn * 64 + ni * 16 + c;
        const float bv = bias[col];
#pragma unroll
        for (int mi = 0; mi < MFR; ++mi)
#pragma unroll
            for (int r = 0; r < 4; ++r) {
                const int row = m0 + wm * (MFR * 16) + mi * 16 + q * 4 + r;
                const float v = (acc[mi][ni][r] + bv) * oscale;
                if constexpr (OMODE == 0) {
                    ((unsigned short*)Cv)[(size_t)row * N + col] = f2bf(v);
                } else if constexpr (OMODE == 1) {
                    const int b = row >> 11, s = row & 2047;
                    ((unsigned short*)Cv)[((size_t)(b * 1024 + col)) * SS + s] = f2bf(v);
                } else {
                    ((float*)Cv)[(size_t)row * N + col] = v;
                }
            }
    }
}

// grid (24 n-tiles, 32 m-tiles): same-W-tile blocks share an XCD (24 % 8 == 0).
__global__ __launch_bounds__(256) void k_gemm_qkv(
    const unsigned short* __restrict__ x, const unsigned short* __restrict__ y,
    const unsigned short* __restrict__ Wq, const float* __restrict__ bq,
    const unsigned short* __restrict__ Wk, const float* __restrict__ bk,
    const unsigned short* __restrict__ Wv, const float* __restrict__ bv,
    unsigned short* __restrict__ Q, unsigned short* __restrict__ Ko,
    unsigned short* __restrict__ Vt)
{
    __shared__ __align__(16) unsigned short As0[128 * 32], As1[128 * 32];
    __shared__ __align__(16) unsigned short Bs0[128 * 32], Bs1[128 * 32];
    const int m0 = blockIdx.y * 128;
    const int nt = blockIdx.x;
    const int g = nt >> 3;
    const int n0 = (nt & 7) * 128;
    if (g == 0) {
        gemm_body<128, 0>(x, Wq, bq, Q, QSCALE, m0, n0, As0, As1, Bs0, Bs1);
    } else if (g == 1) {
        gemm_body<128, 0>(y, Wk, bk, Ko, 1.0f, m0, n0, As0, As1, Bs0, Bs1);
    } else {
        gemm_body<128, 1>(y, Wv, bv, Vt, 1.0f, m0, n0, As0, As1, Bs0, Bs1);
    }
}

// grid (8 n-tiles, 64 m-tiles), fp32 output.
__global__ __launch_bounds__(256) void k_gemm_out(
    const unsigned short* __restrict__ A, const unsigned short* __restrict__ W,
    const float* __restrict__ bias, float* __restrict__ C)
{
    __shared__ __align__(16) unsigned short As0[64 * 32], As1[64 * 32];
    __shared__ __align__(16) unsigned short Bs0[128 * 32], Bs1[128 * 32];
    gemm_body<64, 2>(A, W, bias, C, 1.0f, blockIdx.y * 64, blockIdx.x * 128,
                     As0, As1, Bs0, Bs1);
}

// ---------------------------------------------------------------------------
// Flash attention v7: VALU diet + unfenced scheduler.
// R2 post-mortem: occupancy 2x (R1) and load-latency hiding (R2) both flat at
// ~67-69us; time tracks total per-CU work -> a work pipe is the limiter, and
// VALUBusy (56%) is the highest. VALU hogs found by instruction accounting:
// (1) exp2f w/o fast-math expands to ~5-op libm fixup x32/wave-iter -> use
//     raw __builtin_amdgcn_exp2f (v_exp_f32; scores |s|<~8, 1-ulp safe);
// (2) s_setprio intrinsics are side-effecting scheduler FENCES: exp2/pack of
//     slice tt+1 could not interleave with PV MFMAs of slice tt -> removed,
//     and SM->PV fused per-tt at source so slice-level independence is
//     explicit in one basic block;
// (3) DS addresses recomputed every iter (buffer parity flips) -> unroll 2
//     makes parity compile-time so LICM hoists the 24 read addresses.
// R3 result: 67.4 -> 51.9us, VALUBusy 56 -> 38, MfmaUtil 35 -> 46. ~663 TF.
// Structure: 8 waves, split-K halves, dbuf LDS + reg prefetch, one
// barrier/iter, additive combine (no running max; pre-scaled exp2).
// ---------------------------------------------------------------------------
__global__ __launch_bounds__(512, 4) void k_attn(
    const unsigned short* __restrict__ Q, const unsigned short* __restrict__ K,
    const unsigned short* __restrict__ Vt, unsigned short* __restrict__ O)
{
    constexpr int LDK = 72;             // b128 frag reads: depth-8 uniform
    constexpr int TSZ = 64 * LDK + 64 * 64;  // ushorts per K+V buffer
    __shared__ __align__(16) unsigned short smem[2 * 2 * TSZ];  // 69632 B
    float* Ob = (float*)smem;           // combine reuse: [128][66] fp32

    const int bh = blockIdx.x, qt = blockIdx.y;
    const int b = bh >> 4, h = bh & 15;
    const int t = threadIdx.x, w = t >> 6;
    const int ws = w >> 2;   // key half: 0 -> keys [0,1024), 1 -> [1024,2048)
    const int wq = w & 3;    // Q-row group within the 128-row tile
    const int lane = t & 63, q = lane >> 4, c = lane & 15;

    unsigned short* Sb = smem + ws * (2 * TSZ);  // this half's buffer pair

    // Q B-frags (B[k=d=q*8+j][n=qrow=c]), two 16-row groups per wave.
    short8 qb[2][2];
#pragma unroll
    for (int g = 0; g < 2; ++g) {
        const size_t qoff =
            (size_t)(b * SS + qt * 128 + wq * 32 + g * 16 + c) * EE + h * DD + q * 8;
        qb[g][0] = *(const short8*)(Q + qoff);
        qb[g][1] = *(const short8*)(Q + qoff + 32);
    }

    floatx4 o[2][4] = {};
    floatx4 lacc[2] = {};
    const shortx4 ones = {(short)0x3F80, (short)0x3F80, (short)0x3F80, (short)0x3F80};

    // staging: each 256-thread half stages its own K/V tile (64 keys x 64 d).
    const int ts = t & 255;
    const int sr = ts >> 2, sp = (ts & 3) * 16;  // staging row / col chunk
    const int vkey = (sr & 15) << 2;
    const unsigned short* Kg =
        K + (size_t)(b * SS + ws * 1024 + sr) * EE + h * DD + sp;
    const unsigned short* Vg =
        Vt + ((size_t)bh * DD + sr) * SS + ws * 1024 + sp;

    // prologue: tile 0 -> buf 0
    {
        const ushort8* gk = (const ushort8*)Kg;
        ushort8 k0 = gk[0], k1 = gk[1];
        const ushort8* gv = (const ushort8*)Vg;
        ushort8 v0 = gv[0], v1 = gv[1];
        unsigned short* Ks = Sb;
        unsigned short* Vs = Sb + 64 * LDK;
        *(ushort8*)&Ks[sr * LDK + sp] = k0;
        *(ushort8*)&Ks[sr * LDK + sp + 8] = k1;
        *(ush4*)&Vs[sr * 64 + ((sp +  0) ^ vkey)] =
            __builtin_shufflevector(v0, v0, 0, 1, 2, 3);
        *(ush4*)&Vs[sr * 64 + ((sp +  4) ^ vkey)] =
            __builtin_shufflevector(v0, v0, 4, 5, 6, 7);
        *(ush4*)&Vs[sr * 64 + ((sp +  8) ^ vkey)] =
            __builtin_shufflevector(v1, v1, 0, 1, 2, 3);
        *(ush4*)&Vs[sr * 64 + ((sp + 12) ^ vkey)] =
            __builtin_shufflevector(v1, v1, 4, 5, 6, 7);
    }

#pragma unroll 2
    for (int it = 0; it < 16; ++it) {
        const unsigned short* Ks = Sb + (it & 1) * TSZ;
        const unsigned short* Vs = Ks + 64 * LDK;
        __syncthreads();  // buf[it&1] writes visible; prev reads complete

        // issue next-tile loads (wrap at tail: it=15 re-reads tile 0, whose
        // write lands in buf0 which is never read again -- keeps the loads
        // unconditional so the scheduler can't sink them past the compute).
        const int nit = (it + 1) & 15;
        ushort8 pk0, pk1, pv0, pv1;
        {
            const ushort8* gk = (const ushort8*)(Kg + (size_t)nit * 64 * EE);
            pk0 = gk[0]; pk1 = gk[1];
            const ushort8* gv = (const ushort8*)(Vg + nit * 64);
            pv0 = gv[0]; pv1 = gv[1];
        }

        // Fused per-K-slice: S^T (A = K rows sk=tt*16+c, B = Q rows) -> exp2
        // -> pack -> PV + lsum. Lane: P[sk=tt*16+q*4+r][qrow=c]. Slices are
        // independent (o-accum distance = 10 MFMA16s) -> scheduler overlaps
        // slice tt+1's trans/VALU with slice tt's MFMA16s.
#pragma unroll
        for (int tt = 0; tt < 4; ++tt) {
            const short8 ka0 = *(const short8*)&Ks[(tt * 16 + c) * LDK + q * 8];
            const short8 ka1 = *(const short8*)&Ks[(tt * 16 + c) * LDK + 32 + q * 8];
            shortx4 pa[2];
#pragma unroll
            for (int g = 0; g < 2; ++g) {
                floatx4 s = {0.f, 0.f, 0.f, 0.f};
                s = MFMA32(ka0, qb[g][0], s);
                s = MFMA32(ka1, qb[g][1], s);
                union { unsigned int u[2]; shortx4 v; } pk;
                pk.u[0] = pkbf(__builtin_amdgcn_exp2f(s[0]),
                               __builtin_amdgcn_exp2f(s[1]));
                pk.u[1] = pkbf(__builtin_amdgcn_exp2f(s[2]),
                               __builtin_amdgcn_exp2f(s[3]));
                pa[g] = pk.v;
            }
            // O += P*V: A[m=qrow=c][k=q*4+j]; B[k][n=dv=c] from swizzled Vs.
#pragma unroll
            for (int nd = 0; nd < 4; ++nd) {
                const shortx4 vb = *(const shortx4*)
                    &Vs[(nd * 16 + c) * 64 + (((tt * 4 + q) ^ c) << 2)];
                o[0][nd] = MFMA16(pa[0], vb, o[0][nd]);
                o[1][nd] = MFMA16(pa[1], vb, o[1][nd]);
            }
            lacc[0] = MFMA16(pa[0], ones, lacc[0]);
            lacc[1] = MFMA16(pa[1], ones, lacc[1]);
        }

        // write prefetched tile -> other buffer (vmcnt drain hidden by compute)
        {
            unsigned short* Kn = Sb + ((it + 1) & 1) * TSZ;
            unsigned short* Vn = Kn + 64 * LDK;
            *(ushort8*)&Kn[sr * LDK + sp] = pk0;
            *(ushort8*)&Kn[sr * LDK + sp + 8] = pk1;
            *(ush4*)&Vn[sr * 64 + ((sp +  0) ^ vkey)] =
                __builtin_shufflevector(pv0, pv0, 0, 1, 2, 3);
            *(ush4*)&Vn[sr * 64 + ((sp +  4) ^ vkey)] =
                __builtin_shufflevector(pv0, pv0, 4, 5, 6, 7);
            *(ush4*)&Vn[sr * 64 + ((sp +  8) ^ vkey)] =
                __builtin_shufflevector(pv1, pv1, 0, 1, 2, 3);
            *(ush4*)&Vn[sr * 64 + ((sp + 12) ^ vkey)] =
                __builtin_shufflevector(pv1, pv1, 4, 5, 6, 7);
        }
    }

    // ---- combine the two key halves (additive: no running max) ----
    __syncthreads();  // all staging traffic done; safe to reuse smem as Ob
    if (ws == 1) {
#pragma unroll
        for (int g = 0; g < 2; ++g) {
#pragma unroll
            for (int nd = 0; nd < 4; ++nd)
#pragma unroll
                for (int r = 0; r < 4; ++r)
                    Ob[(wq * 32 + g * 16 + q * 4 + r) * 66 + nd * 16 + c] =
                        o[g][nd][r];
            if (c == 0) {
#pragma unroll
                for (int r = 0; r < 4; ++r)
                    Ob[(wq * 32 + g * 16 + q * 4 + r) * 66 + 64] = lacc[g][r];
            }
        }
    }
    __syncthreads();
    if (ws == 0) {
#pragma unroll
        for (int g = 0; g < 2; ++g) {
            float linv[4];
#pragma unroll
            for (int r = 0; r < 4; ++r) {
                const int rr = wq * 32 + g * 16 + q * 4 + r;
#pragma unroll
                for (int nd = 0; nd < 4; ++nd)
                    o[g][nd][r] += Ob[rr * 66 + nd * 16 + c];
                linv[r] = __builtin_amdgcn_rcpf(lacc[g][r] + Ob[rr * 66 + 64]);
            }
            const int orow = b * SS + qt * 128 + wq * 32 + g * 16;
#pragma unroll
            for (int nd = 0; nd < 4; ++nd)
#pragma unroll
                for (int r = 0; r < 4; ++r)
                    O[(size_t)(orow + q * 4 + r) * EE + h * DD + nd * 16 + c] =
                        f2bf(o[g][nd][r] * linv[r]);
        }
    }
}

// ---------------------------------------------------------------------------
extern "C" void kernel_launch(void* const* d_in, const int* in_sizes, int n_in,
                              void* d_out, int out_size, void* d_ws, size_t ws_size,
                              hipStream_t stream)
{
    const float* x  = (const float*)d_in[0];
    const float* y  = (const float*)d_in[1];
    // d_in[2] = mask (int32) — faithfully ignored, as in the reference
    const float* Wq = (const float*)d_in[3];
    const float* bq = (const float*)d_in[4];
    const float* Wk = (const float*)d_in[5];
    const float* bk = (const float*)d_in[6];
    const float* Wv = (const float*)d_in[7];
    const float* bv = (const float*)d_in[8];
    const float* Wo = (const float*)d_in[9];
    const float* bo = (const float*)d_in[10];
    float* out = (float*)d_out;

    char* ws = (char*)d_ws;
    const size_t SZ = (size_t)BB * SS * EE * sizeof(unsigned short);  // 8 MiB
    const size_t WZ = (size_t)EE * EE * sizeof(unsigned short);       // 2 MiB
    unsigned short* xb  = (unsigned short*)(ws);
    unsigned short* yb  = (unsigned short*)(ws + SZ);
    unsigned short* Wqb = (unsigned short*)(ws + 2 * SZ);
    unsigned short* Wkb = (unsigned short*)(ws + 2 * SZ + WZ);
    unsigned short* Wvb = (unsigned short*)(ws + 2 * SZ + 2 * WZ);
    unsigned short* Wob = (unsigned short*)(ws + 2 * SZ + 3 * WZ);
    unsigned short* Qw  = (unsigned short*)(ws + 2 * SZ + 4 * WZ);
    unsigned short* Kw  = (unsigned short*)(ws + 3 * SZ + 4 * WZ);
    unsigned short* Vtw = (unsigned short*)(ws + 4 * SZ + 4 * WZ);
    unsigned short* Aw  = (unsigned short*)(ws + 5 * SZ + 4 * WZ);
    (void)ws_size; (void)in_sizes; (void)n_in; (void)out_size;

    k_cvt<<<dim3(1024, 6), 256, 0, stream>>>(x, xb, y, yb, Wq, Wqb, Wk, Wkb,
                                             Wv, Wvb, Wo, Wob);
    k_gemm_qkv<<<dim3(24, 32), 256, 0, stream>>>(xb, yb, Wqb, bq, Wkb, bk, Wvb, bv,
                                                 Qw, Kw, Vtw);
    k_attn<<<dim3(32, 16), 512, 0, stream>>>(Qw, Kw, Vtw, Aw);
    k_gemm_out<<<dim3(8, 64), 256, 0, stream>>>(Aw, Wob, bo, out);
}

// Round 5
// 231.599 us; speedup vs baseline: 1.0072x; 1.0072x over previous
//
#include <hip/hip_runtime.h>
#include <cstdint>
#include <cstddef>

// Problem constants
#define BB 2
#define SS 2048
#define EE 1024
#define HH 16
#define DD 64

typedef __attribute__((ext_vector_type(8))) short short8;           // 16x16x32 A/B frag
typedef __attribute__((ext_vector_type(4))) short shortx4;          // 16x16x16 A/B frag
typedef __attribute__((ext_vector_type(8))) unsigned short ushort8; // 16B vector ld/st
typedef __attribute__((ext_vector_type(4))) unsigned short ush4;    // 8B vector st
typedef __attribute__((ext_vector_type(4))) float floatx4;          // MFMA C/D frag / float4

#define MFMA32(a, b, c) __builtin_amdgcn_mfma_f32_16x16x32_bf16((a), (b), (c), 0, 0, 0)
#define MFMA16(a, b, c) __builtin_amdgcn_mfma_f32_16x16x16bf16_1k((a), (b), (c), 0, 0, 0)

// 0.125 (1/sqrt(64)) * log2(e): folded into Q so attn can use exp2 directly.
#define QSCALE 0.18033688011112042f

// direct global->LDS async copy, 16B/lane; LDS dest = wave-uniform base + lane*16
#define G2L16(g, l)                                                        \
    __builtin_amdgcn_global_load_lds(                                      \
        (const __attribute__((address_space(1))) void*)(g),                \
        (__attribute__((address_space(3))) void*)(l), 16, 0, 0)

// float -> bf16 bits, round-to-nearest-even
__device__ __forceinline__ unsigned short f2bf(float f) {
    unsigned int u = __float_as_uint(f);
    u += 0x7fffu + ((u >> 16) & 1u);
    return (unsigned short)(u >> 16);
}

// pack two floats into bf16x2 (round-half-up): 2 adds + 1 v_perm
__device__ __forceinline__ unsigned int pkbf(float a, float b) {
    return __builtin_amdgcn_perm(__float_as_uint(b) + 0x8000u,
                                 __float_as_uint(a) + 0x8000u, 0x07060302u);
}

// ---------------------------------------------------------------------------
// fp32 -> bf16 bulk converter, all 6 tensors in one launch.
// grid (1024, 6): g 0..1 -> x,y (1024 blocks); g 2..5 -> W (256 blocks each).
// ---------------------------------------------------------------------------
__global__ __launch_bounds__(256) void k_cvt(
    const float* __restrict__ x, unsigned short* __restrict__ xb,
    const float* __restrict__ y, unsigned short* __restrict__ yb,
    const float* __restrict__ w0, unsigned short* __restrict__ d0,
    const float* __restrict__ w1, unsigned short* __restrict__ d1,
    const float* __restrict__ w2, unsigned short* __restrict__ d2,
    const float* __restrict__ w3, unsigned short* __restrict__ d3)
{
    const int g = blockIdx.y;
    if (g >= 2 && blockIdx.x >= 256) return;
    const float* s = (g == 0) ? x : (g == 1) ? y : (g == 2) ? w0
                   : (g == 3) ? w1 : (g == 4) ? w2 : w3;
    unsigned short* d = (g == 0) ? xb : (g == 1) ? yb : (g == 2) ? d0
                      : (g == 3) ? d1 : (g == 4) ? d2 : d3;
    const size_t i = ((size_t)blockIdx.x * 256 + threadIdx.x) * 16;
    floatx4 f0 = *(const floatx4*)(s + i);
    floatx4 f1 = *(const floatx4*)(s + i + 4);
    floatx4 f2 = *(const floatx4*)(s + i + 8);
    floatx4 f3 = *(const floatx4*)(s + i + 12);
    ushort8 o0, o1;
#pragma unroll
    for (int j = 0; j < 4; ++j) { o0[j] = f2bf(f0[j]); o0[j + 4] = f2bf(f1[j]); }
#pragma unroll
    for (int j = 0; j < 4; ++j) { o1[j] = f2bf(f2[j]); o1[j + 4] = f2bf(f3[j]); }
    *(ushort8*)(d + i) = o0;
    *(ushort8*)(d + i + 8) = o1;
}

// ---------------------------------------------------------------------------
// GEMM: C[M,N] = (A[M,K] * W[N,K]^T + bias[N]) * oscale, bf16 in, fp32 accum.
// v3 (R5): counted vmcnt + raw barriers (T4). R4 post-mortem: the 2-phase
// dbuf was nullified by __syncthreads' implicit vmcnt(0) drain (replicates
// m99/m100); MfmaUtil 18%, everything idle -> per-phase wall ~4000cy vs
// ~900cy of work. Fix = the m218 counted-vmcnt recipe. Per phase:
//   s_barrier                    // WAR: compute(p-1) ds_reads done (data in
//                                //      VGPRs before waves reach barrier)
//   issue G2L16 loads(p+1)       // -> buf[other]
//   s_waitcnt vmcnt(KEEP)        // KEEP = loads/phase: waits loads(p) only,
//   s_barrier                    //   loads(p+1) STAY IN FLIGHT across phase
//   compute(buf[cur])
// RAW: every wave passed its own vmcnt(KEEP) => all tile-p LDS writes landed
// => barrier => visible. Dead wrap-stage at the tail keeps loads in the main
// BB. sched_barrier(0) after the 2nd barrier pins ds_reads behind the wait.
// OMODE: 0 = bf16 row-major [M][1024], 1 = bf16 V-transposed [b*1024+col][2048],
//        2 = fp32 row-major [M][1024].
// ---------------------------------------------------------------------------
template <int MT, int OMODE>
__device__ __forceinline__ void gemm_body(
    const unsigned short* __restrict__ A, const unsigned short* __restrict__ W,
    const float* __restrict__ bias, void* __restrict__ Cv, float oscale,
    int m0, int n0, unsigned short* As0, unsigned short* As1,
    unsigned short* Bs0, unsigned short* Bs1)
{
    constexpr int K = 1024, N = 1024, LDT = 32;
    constexpr int MFR = MT / 32;  // m-frags per wave (wave tile = MT/2 x 64)
    constexpr int KEEP = (MT == 128) ? 4 : 3;  // G2L16s per phase
    const int t = threadIdx.x;
    const int lane = t & 63, w = t >> 6;
    const int q = lane >> 4, c = lane & 15;
    const int wm = w & 1, wn = w >> 1;
    const int lr = lane >> 2, lc = (lane & 3) * 8;  // 16 rows x 64B per G2L16

    // A staging: wave w covers rows w*(MT/4) .. +(MT/4)-1, in 16-row instrs.
    const unsigned short* gA0 = A + (size_t)(m0 + w * (MT / 4) + lr) * K + lc;
    const unsigned short* gA1 = gA0 + 16 * K;  // MT==128 only
    const unsigned short* gB0 = W + (size_t)(n0 + w * 32 + lr) * K + lc;
    const unsigned short* gB1 = gB0 + 16 * K;
    unsigned short* lA0 = As0 + (w * (MT / 4)) * LDT;  // buf0 A dest
    unsigned short* lA1 = As1 + (w * (MT / 4)) * LDT;  // buf1 A dest
    unsigned short* lB0 = Bs0 + (w * 32) * LDT;
    unsigned short* lB1 = Bs1 + (w * 32) * LDT;

    floatx4 acc[MFR][4] = {};

    // compute one 32-K subtile from buffer (Ah,Bh)
    auto compute = [&](const unsigned short* Ah, const unsigned short* Bh) {
        short8 af[MFR], bfr[4];
#pragma unroll
        for (int mi = 0; mi < MFR; ++mi)
            af[mi] = *(const short8*)
                &Ah[(wm * (MFR * 16) + mi * 16 + c) * LDT + q * 8];
#pragma unroll
        for (int ni = 0; ni < 4; ++ni)
            bfr[ni] = *(const short8*)
                &Bh[(wn * 64 + ni * 16 + c) * LDT + q * 8];
#pragma unroll
        for (int mi = 0; mi < MFR; ++mi)
#pragma unroll
            for (int ni = 0; ni < 4; ++ni)
                acc[mi][ni] = MFMA32(af[mi], bfr[ni], acc[mi][ni]);
    };

    // stage one 32-K subtile (KEEP G2L16 instructions)
    auto stage = [&](int nk, unsigned short* lA, unsigned short* lB) {
        G2L16(gA0 + nk, lA);
        if constexpr (MT == 128) G2L16(gA1 + nk, lA + 16 * LDT);
        G2L16(gB0 + nk, lB);
        G2L16(gB1 + nk, lB + 16 * LDT);
    };

    // prologue: k-subtile 0 -> buffer 0
    stage(0, lA0, lB0);

    for (int kt = 0; kt < K; kt += 64) {
        // --- phase A: prefetch kt+32 -> buf1 (in flight), compute buf0 ---
        __builtin_amdgcn_s_barrier();            // WAR: prev compute done
        stage(kt + 32, lA1, lB1);                // kt <= 960 -> in range
        asm volatile("s_waitcnt vmcnt(%0)" :: "n"(KEEP) : "memory");
        __builtin_amdgcn_s_barrier();            // RAW: buf0 ready for all
        __builtin_amdgcn_sched_barrier(0);
        compute(As0, Bs0);
        // --- phase B: prefetch kt+64 -> buf0 (in flight), compute buf1 ---
        __builtin_amdgcn_s_barrier();
        stage((kt + 64) & (K - 1), lA0, lB0);    // wraps to dead re-stage of
        asm volatile("s_waitcnt vmcnt(%0)" :: "n"(KEEP) : "memory");  // tile 0
        __builtin_amdgcn_s_barrier();            // on the last phase (keeps
        __builtin_amdgcn_sched_barrier(0);       // loads unconditional)
        compute(As1, Bs1);
    }

#pragma unroll
    for (int ni = 0; ni < 4; ++ni) {
        const int col = n0 + wn * 64 + ni * 16 + c;
        const float bv = bias[col];
#pragma unroll
        for (int mi = 0; mi < MFR; ++mi)
#pragma unroll
            for (int r = 0; r < 4; ++r) {
                const int row = m0 + wm * (MFR * 16) + mi * 16 + q * 4 + r;
                const float v = (acc[mi][ni][r] + bv) * oscale;
                if constexpr (OMODE == 0) {
                    ((unsigned short*)Cv)[(size_t)row * N + col] = f2bf(v);
                } else if constexpr (OMODE == 1) {
                    const int b = row >> 11, s = row & 2047;
                    ((unsigned short*)Cv)[((size_t)(b * 1024 + col)) * SS + s] = f2bf(v);
                } else {
                    ((float*)Cv)[(size_t)row * N + col] = v;
                }
            }
    }
}

// grid (24 n-tiles, 32 m-tiles): same-W-tile blocks share an XCD (24 % 8 == 0).
__global__ __launch_bounds__(256) void k_gemm_qkv(
    const unsigned short* __restrict__ x, const unsigned short* __restrict__ y,
    const unsigned short* __restrict__ Wq, const float* __restrict__ bq,
    const unsigned short* __restrict__ Wk, const float* __restrict__ bk,
    const unsigned short* __restrict__ Wv, const float* __restrict__ bv,
    unsigned short* __restrict__ Q, unsigned short* __restrict__ Ko,
    unsigned short* __restrict__ Vt)
{
    __shared__ __align__(16) unsigned short As0[128 * 32], As1[128 * 32];
    __shared__ __align__(16) unsigned short Bs0[128 * 32], Bs1[128 * 32];
    const int m0 = blockIdx.y * 128;
    const int nt = blockIdx.x;
    const int g = nt >> 3;
    const int n0 = (nt & 7) * 128;
    if (g == 0) {
        gemm_body<128, 0>(x, Wq, bq, Q, QSCALE, m0, n0, As0, As1, Bs0, Bs1);
    } else if (g == 1) {
        gemm_body<128, 0>(y, Wk, bk, Ko, 1.0f, m0, n0, As0, As1, Bs0, Bs1);
    } else {
        gemm_body<128, 1>(y, Wv, bv, Vt, 1.0f, m0, n0, As0, As1, Bs0, Bs1);
    }
}

// grid (8 n-tiles, 64 m-tiles), fp32 output.
__global__ __launch_bounds__(256) void k_gemm_out(
    const unsigned short* __restrict__ A, const unsigned short* __restrict__ W,
    const float* __restrict__ bias, float* __restrict__ C)
{
    __shared__ __align__(16) unsigned short As0[64 * 32], As1[64 * 32];
    __shared__ __align__(16) unsigned short Bs0[128 * 32], Bs1[128 * 32];
    gemm_body<64, 2>(A, W, bias, C, 1.0f, blockIdx.y * 64, blockIdx.x * 128,
                     As0, As1, Bs0, Bs1);
}

// ---------------------------------------------------------------------------
// Flash attention v7: VALU diet + unfenced scheduler.
// R2 post-mortem: occupancy 2x (R1) and load-latency hiding (R2) both flat at
// ~67-69us; time tracks total per-CU work -> a work pipe is the limiter, and
// VALUBusy (56%) is the highest. VALU hogs found by instruction accounting:
// (1) exp2f w/o fast-math expands to ~5-op libm fixup x32/wave-iter -> use
//     raw __builtin_amdgcn_exp2f (v_exp_f32; scores |s|<~8, 1-ulp safe);
// (2) s_setprio intrinsics are side-effecting scheduler FENCES: exp2/pack of
//     slice tt+1 could not interleave with PV MFMAs of slice tt -> removed,
//     and SM->PV fused per-tt at source so slice-level independence is
//     explicit in one basic block;
// (3) DS addresses recomputed every iter (buffer parity flips) -> unroll 2
//     makes parity compile-time so LICM hoists the 24 read addresses.
// R3 result: 67.4 -> 51.9us, VALUBusy 56 -> 38, MfmaUtil 35 -> 46. ~663 TF.
// Structure: 8 waves, split-K halves, dbuf LDS + reg prefetch, one
// barrier/iter, additive combine (no running max; pre-scaled exp2).
// ---------------------------------------------------------------------------
__global__ __launch_bounds__(512, 4) void k_attn(
    const unsigned short* __restrict__ Q, const unsigned short* __restrict__ K,
    const unsigned short* __restrict__ Vt, unsigned short* __restrict__ O)
{
    constexpr int LDK = 72;             // b128 frag reads: depth-8 uniform
    constexpr int TSZ = 64 * LDK + 64 * 64;  // ushorts per K+V buffer
    __shared__ __align__(16) unsigned short smem[2 * 2 * TSZ];  // 69632 B
    float* Ob = (float*)smem;           // combine reuse: [128][66] fp32

    const int bh = blockIdx.x, qt = blockIdx.y;
    const int b = bh >> 4, h = bh & 15;
    const int t = threadIdx.x, w = t >> 6;
    const int ws = w >> 2;   // key half: 0 -> keys [0,1024), 1 -> [1024,2048)
    const int wq = w & 3;    // Q-row group within the 128-row tile
    const int lane = t & 63, q = lane >> 4, c = lane & 15;

    unsigned short* Sb = smem + ws * (2 * TSZ);  // this half's buffer pair

    // Q B-frags (B[k=d=q*8+j][n=qrow=c]), two 16-row groups per wave.
    short8 qb[2][2];
#pragma unroll
    for (int g = 0; g < 2; ++g) {
        const size_t qoff =
            (size_t)(b * SS + qt * 128 + wq * 32 + g * 16 + c) * EE + h * DD + q * 8;
        qb[g][0] = *(const short8*)(Q + qoff);
        qb[g][1] = *(const short8*)(Q + qoff + 32);
    }

    floatx4 o[2][4] = {};
    floatx4 lacc[2] = {};
    const shortx4 ones = {(short)0x3F80, (short)0x3F80, (short)0x3F80, (short)0x3F80};

    // staging: each 256-thread half stages its own K/V tile (64 keys x 64 d).
    const int ts = t & 255;
    const int sr = ts >> 2, sp = (ts & 3) * 16;  // staging row / col chunk
    const int vkey = (sr & 15) << 2;
    const unsigned short* Kg =
        K + (size_t)(b * SS + ws * 1024 + sr) * EE + h * DD + sp;
    const unsigned short* Vg =
        Vt + ((size_t)bh * DD + sr) * SS + ws * 1024 + sp;

    // prologue: tile 0 -> buf 0
    {
        const ushort8* gk = (const ushort8*)Kg;
        ushort8 k0 = gk[0], k1 = gk[1];
        const ushort8* gv = (const ushort8*)Vg;
        ushort8 v0 = gv[0], v1 = gv[1];
        unsigned short* Ks = Sb;
        unsigned short* Vs = Sb + 64 * LDK;
        *(ushort8*)&Ks[sr * LDK + sp] = k0;
        *(ushort8*)&Ks[sr * LDK + sp + 8] = k1;
        *(ush4*)&Vs[sr * 64 + ((sp +  0) ^ vkey)] =
            __builtin_shufflevector(v0, v0, 0, 1, 2, 3);
        *(ush4*)&Vs[sr * 64 + ((sp +  4) ^ vkey)] =
            __builtin_shufflevector(v0, v0, 4, 5, 6, 7);
        *(ush4*)&Vs[sr * 64 + ((sp +  8) ^ vkey)] =
            __builtin_shufflevector(v1, v1, 0, 1, 2, 3);
        *(ush4*)&Vs[sr * 64 + ((sp + 12) ^ vkey)] =
            __builtin_shufflevector(v1, v1, 4, 5, 6, 7);
    }

#pragma unroll 2
    for (int it = 0; it < 16; ++it) {
        const unsigned short* Ks = Sb + (it & 1) * TSZ;
        const unsigned short* Vs = Ks + 64 * LDK;
        __syncthreads();  // buf[it&1] writes visible; prev reads complete

        // issue next-tile loads (wrap at tail: it=15 re-reads tile 0, whose
        // write lands in buf0 which is never read again -- keeps the loads
        // unconditional so the scheduler can't sink them past the compute).
        const int nit = (it + 1) & 15;
        ushort8 pk0, pk1, pv0, pv1;
        {
            const ushort8* gk = (const ushort8*)(Kg + (size_t)nit * 64 * EE);
            pk0 = gk[0]; pk1 = gk[1];
            const ushort8* gv = (const ushort8*)(Vg + nit * 64);
            pv0 = gv[0]; pv1 = gv[1];
        }

        // Fused per-K-slice: S^T (A = K rows sk=tt*16+c, B = Q rows) -> exp2
        // -> pack -> PV + lsum. Lane: P[sk=tt*16+q*4+r][qrow=c]. Slices are
        // independent (o-accum distance = 10 MFMA16s) -> scheduler overlaps
        // slice tt+1's trans/VALU with slice tt's MFMA16s.
#pragma unroll
        for (int tt = 0; tt < 4; ++tt) {
            const short8 ka0 = *(const short8*)&Ks[(tt * 16 + c) * LDK + q * 8];
            const short8 ka1 = *(const short8*)&Ks[(tt * 16 + c) * LDK + 32 + q * 8];
            shortx4 pa[2];
#pragma unroll
            for (int g = 0; g < 2; ++g) {
                floatx4 s = {0.f, 0.f, 0.f, 0.f};
                s = MFMA32(ka0, qb[g][0], s);
                s = MFMA32(ka1, qb[g][1], s);
                union { unsigned int u[2]; shortx4 v; } pk;
                pk.u[0] = pkbf(__builtin_amdgcn_exp2f(s[0]),
                               __builtin_amdgcn_exp2f(s[1]));
                pk.u[1] = pkbf(__builtin_amdgcn_exp2f(s[2]),
                               __builtin_amdgcn_exp2f(s[3]));
                pa[g] = pk.v;
            }
            // O += P*V: A[m=qrow=c][k=q*4+j]; B[k][n=dv=c] from swizzled Vs.
#pragma unroll
            for (int nd = 0; nd < 4; ++nd) {
                const shortx4 vb = *(const shortx4*)
                    &Vs[(nd * 16 + c) * 64 + (((tt * 4 + q) ^ c) << 2)];
                o[0][nd] = MFMA16(pa[0], vb, o[0][nd]);
                o[1][nd] = MFMA16(pa[1], vb, o[1][nd]);
            }
            lacc[0] = MFMA16(pa[0], ones, lacc[0]);
            lacc[1] = MFMA16(pa[1], ones, lacc[1]);
        }

        // write prefetched tile -> other buffer (vmcnt drain hidden by compute)
        {
            unsigned short* Kn = Sb + ((it + 1) & 1) * TSZ;
            unsigned short* Vn = Kn + 64 * LDK;
            *(ushort8*)&Kn[sr * LDK + sp] = pk0;
            *(ushort8*)&Kn[sr * LDK + sp + 8] = pk1;
            *(ush4*)&Vn[sr * 64 + ((sp +  0) ^ vkey)] =
                __builtin_shufflevector(pv0, pv0, 0, 1, 2, 3);
            *(ush4*)&Vn[sr * 64 + ((sp +  4) ^ vkey)] =
                __builtin_shufflevector(pv0, pv0, 4, 5, 6, 7);
            *(ush4*)&Vn[sr * 64 + ((sp +  8) ^ vkey)] =
                __builtin_shufflevector(pv1, pv1, 0, 1, 2, 3);
            *(ush4*)&Vn[sr * 64 + ((sp + 12) ^ vkey)] =
                __builtin_shufflevector(pv1, pv1, 4, 5, 6, 7);
        }
    }

    // ---- combine the two key halves (additive: no running max) ----
    __syncthreads();  // all staging traffic done; safe to reuse smem as Ob
    if (ws == 1) {
#pragma unroll
        for (int g = 0; g < 2; ++g) {
#pragma unroll
            for (int nd = 0; nd < 4; ++nd)
#pragma unroll
                for (int r = 0; r < 4; ++r)
                    Ob[(wq * 32 + g * 16 + q * 4 + r) * 66 + nd * 16 + c] =
                        o[g][nd][r];
            if (c == 0) {
#pragma unroll
                for (int r = 0; r < 4; ++r)
                    Ob[(wq * 32 + g * 16 + q * 4 + r) * 66 + 64] = lacc[g][r];
            }
        }
    }
    __syncthreads();
    if (ws == 0) {
#pragma unroll
        for (int g = 0; g < 2; ++g) {
            float linv[4];
#pragma unroll
            for (int r = 0; r < 4; ++r) {
                const int rr = wq * 32 + g * 16 + q * 4 + r;
#pragma unroll
                for (int nd = 0; nd < 4; ++nd)
                    o[g][nd][r] += Ob[rr * 66 + nd * 16 + c];
                linv[r] = __builtin_amdgcn_rcpf(lacc[g][r] + Ob[rr * 66 + 64]);
            }
            const int orow = b * SS + qt * 128 + wq * 32 + g * 16;
#pragma unroll
            for (int nd = 0; nd < 4; ++nd)
#pragma unroll
                for (int r = 0; r < 4; ++r)
                    O[(size_t)(orow + q * 4 + r) * EE + h * DD + nd * 16 + c] =
                        f2bf(o[g][nd][r] * linv[r]);
        }
    }
}

// ---------------------------------------------------------------------------
extern "C" void kernel_launch(void* const* d_in, const int* in_sizes, int n_in,
                              void* d_out, int out_size, void* d_ws, size_t ws_size,
                              hipStream_t stream)
{
    const float* x  = (const float*)d_in[0];
    const float* y  = (const float*)d_in[1];
    // d_in[2] = mask (int32) — faithfully ignored, as in the reference
    const float* Wq = (const float*)d_in[3];
    const float* bq = (const float*)d_in[4];
    const float* Wk = (const float*)d_in[5];
    const float* bk = (const float*)d_in[6];
    const float* Wv = (const float*)d_in[7];
    const float* bv = (const float*)d_in[8];
    const float* Wo = (const float*)d_in[9];
    const float* bo = (const float*)d_in[10];
    float* out = (float*)d_out;

    char* ws = (char*)d_ws;
    const size_t SZ = (size_t)BB * SS * EE * sizeof(unsigned short);  // 8 MiB
    const size_t WZ = (size_t)EE * EE * sizeof(unsigned short);       // 2 MiB
    unsigned short* xb  = (unsigned short*)(ws);
    unsigned short* yb  = (unsigned short*)(ws + SZ);
    unsigned short* Wqb = (unsigned short*)(ws + 2 * SZ);
    unsigned short* Wkb = (unsigned short*)(ws + 2 * SZ + WZ);
    unsigned short* Wvb = (unsigned short*)(ws + 2 * SZ + 2 * WZ);
    unsigned short* Wob = (unsigned short*)(ws + 2 * SZ + 3 * WZ);
    unsigned short* Qw  = (unsigned short*)(ws + 2 * SZ + 4 * WZ);
    unsigned short* Kw  = (unsigned short*)(ws + 3 * SZ + 4 * WZ);
    unsigned short* Vtw = (unsigned short*)(ws + 4 * SZ + 4 * WZ);
    unsigned short* Aw  = (unsigned short*)(ws + 5 * SZ + 4 * WZ);
    (void)ws_size; (void)in_sizes; (void)n_in; (void)out_size;

    k_cvt<<<dim3(1024, 6), 256, 0, stream>>>(x, xb, y, yb, Wq, Wqb, Wk, Wkb,
                                             Wv, Wvb, Wo, Wob);
    k_gemm_qkv<<<dim3(24, 32), 256, 0, stream>>>(xb, yb, Wqb, bq, Wkb, bk, Wvb, bv,
                                                 Qw, Kw, Vtw);
    k_attn<<<dim3(32, 16), 512, 0, stream>>>(Qw, Kw, Vtw, Aw);
    k_gemm_out<<<dim3(8, 64), 256, 0, stream>>>(Aw, Wob, bo, out);
}

// Round 6
// 226.076 us; speedup vs baseline: 1.0318x; 1.0244x over previous
//
#include <hip/hip_runtime.h>
#include <cstdint>
#include <cstddef>

// Problem constants
#define BB 2
#define SS 2048
#define EE 1024
#define HH 16
#define DD 64

typedef __attribute__((ext_vector_type(8))) short short8;           // 16x16x32 A/B frag
typedef __attribute__((ext_vector_type(4))) short shortx4;          // 16x16x16 A/B frag
typedef __attribute__((ext_vector_type(8))) unsigned short ushort8; // 16B vector ld/st
typedef __attribute__((ext_vector_type(4))) unsigned short ush4;    // 8B vector st
typedef __attribute__((ext_vector_type(4))) float floatx4;          // MFMA C/D frag / float4

#define MFMA32(a, b, c) __builtin_amdgcn_mfma_f32_16x16x32_bf16((a), (b), (c), 0, 0, 0)
#define MFMA16(a, b, c) __builtin_amdgcn_mfma_f32_16x16x16bf16_1k((a), (b), (c), 0, 0, 0)

// 0.125 (1/sqrt(64)) * log2(e): folded into Q so attn can use exp2 directly.
#define QSCALE 0.18033688011112042f

// direct global->LDS async copy, 16B/lane; LDS dest = wave-uniform base + lane*16
#define G2L16(g, l)                                                        \
    __builtin_amdgcn_global_load_lds(                                      \
        (const __attribute__((address_space(1))) void*)(g),                \
        (__attribute__((address_space(3))) void*)(l), 16, 0, 0)

// float -> bf16 bits, round-to-nearest-even
__device__ __forceinline__ unsigned short f2bf(float f) {
    unsigned int u = __float_as_uint(f);
    u += 0x7fffu + ((u >> 16) & 1u);
    return (unsigned short)(u >> 16);
}

// pack two floats into bf16x2 (round-half-up): 2 adds + 1 v_perm
__device__ __forceinline__ unsigned int pkbf(float a, float b) {
    return __builtin_amdgcn_perm(__float_as_uint(b) + 0x8000u,
                                 __float_as_uint(a) + 0x8000u, 0x07060302u);
}

// ---------------------------------------------------------------------------
// fp32 -> bf16 bulk converter, all 6 tensors in one launch.
// grid (1024, 6): g 0..1 -> x,y (1024 blocks); g 2..5 -> W (256 blocks each).
// ---------------------------------------------------------------------------
__global__ __launch_bounds__(256) void k_cvt(
    const float* __restrict__ x, unsigned short* __restrict__ xb,
    const float* __restrict__ y, unsigned short* __restrict__ yb,
    const float* __restrict__ w0, unsigned short* __restrict__ d0,
    const float* __restrict__ w1, unsigned short* __restrict__ d1,
    const float* __restrict__ w2, unsigned short* __restrict__ d2,
    const float* __restrict__ w3, unsigned short* __restrict__ d3)
{
    const int g = blockIdx.y;
    if (g >= 2 && blockIdx.x >= 256) return;
    const float* s = (g == 0) ? x : (g == 1) ? y : (g == 2) ? w0
                   : (g == 3) ? w1 : (g == 4) ? w2 : w3;
    unsigned short* d = (g == 0) ? xb : (g == 1) ? yb : (g == 2) ? d0
                      : (g == 3) ? d1 : (g == 4) ? d2 : d3;
    const size_t i = ((size_t)blockIdx.x * 256 + threadIdx.x) * 16;
    floatx4 f0 = *(const floatx4*)(s + i);
    floatx4 f1 = *(const floatx4*)(s + i + 4);
    floatx4 f2 = *(const floatx4*)(s + i + 8);
    floatx4 f3 = *(const floatx4*)(s + i + 12);
    ushort8 o0, o1;
#pragma unroll
    for (int j = 0; j < 4; ++j) { o0[j] = f2bf(f0[j]); o0[j + 4] = f2bf(f1[j]); }
#pragma unroll
    for (int j = 0; j < 4; ++j) { o1[j] = f2bf(f2[j]); o1[j + 4] = f2bf(f3[j]); }
    *(ushort8*)(d + i) = o0;
    *(ushort8*)(d + i + 8) = o1;
}

// ---------------------------------------------------------------------------
// GEMM: C[M,N] = (A[M,K] * W[N,K]^T + bias[N]) * oscale, bf16 in, fp32 accum.
// v4 (R6): 2-deep prefetch, 3 LDS buffers. R5 post-mortem: counted vmcnt with
// 1-phase depth only modestly helped -- per-phase compute (~300cy) covers the
// L2-hit loads (~200-400cy) but not the ~20% HBM-miss staging tail (~900cy;
// FETCH 76MB vs 22MB ideal => real misses every phase). Now: subtile s lives
// in buffer s%3; phase p = { s_barrier; stage(p+2 -> buf[(p+2)%3]);
// s_waitcnt vmcnt(KEEP=2*loads) -- waits loads(p) only, loads(p+1) AND
// loads(p+2) stay in flight; s_barrier; compute(buf[p%3]) }. Coverage is now
// 2 phases (~600-700cy). Hazards (same argument as v3): WAR -- stage(p+2)
// writes the buffer computed at p-1; all of compute(p-1)'s ds_reads are
// lgkm-consumed before its last MFMA, which precedes phase-p's first barrier.
// RAW -- every wave passes vmcnt(KEEP) => all tile-p LDS writes landed =>
// barrier => visible. p%3 made compile-time via 3-phase group body (10
// groups + 2 tail phases); dead wrap-stages keep loads unconditional; final
// vmcnt(0) drains the dead loads before epilogue/endpgm (they target LDS
// that is reallocated to the next block at wave exit).
// OMODE: 0 = bf16 row-major [M][1024], 1 = bf16 V-transposed [b*1024+col][2048],
//        2 = fp32 row-major [M][1024].
// ---------------------------------------------------------------------------
template <int MT, int OMODE>
__device__ __forceinline__ void gemm_body(
    const unsigned short* __restrict__ A, const unsigned short* __restrict__ W,
    const float* __restrict__ bias, void* __restrict__ Cv, float oscale,
    int m0, int n0,
    unsigned short* As0, unsigned short* As1, unsigned short* As2,
    unsigned short* Bs0, unsigned short* Bs1, unsigned short* Bs2)
{
    constexpr int K = 1024, N = 1024, LDT = 32;
    constexpr int MFR = MT / 32;  // m-frags per wave (wave tile = MT/2 x 64)
    constexpr int KEEP = (MT == 128) ? 8 : 6;  // 2 stages (2*loads) in flight
    const int t = threadIdx.x;
    const int lane = t & 63, w = t >> 6;
    const int q = lane >> 4, c = lane & 15;
    const int wm = w & 1, wn = w >> 1;
    const int lr = lane >> 2, lc = (lane & 3) * 8;  // 16 rows x 64B per G2L16

    // A staging: wave w covers rows w*(MT/4) .. +(MT/4)-1, in 16-row instrs.
    const unsigned short* gA0 = A + (size_t)(m0 + w * (MT / 4) + lr) * K + lc;
    const unsigned short* gA1 = gA0 + 16 * K;  // MT==128 only
    const unsigned short* gB0 = W + (size_t)(n0 + w * 32 + lr) * K + lc;
    const unsigned short* gB1 = gB0 + 16 * K;
    unsigned short* lA0 = As0 + (w * (MT / 4)) * LDT;
    unsigned short* lA1 = As1 + (w * (MT / 4)) * LDT;
    unsigned short* lA2 = As2 + (w * (MT / 4)) * LDT;
    unsigned short* lB0 = Bs0 + (w * 32) * LDT;
    unsigned short* lB1 = Bs1 + (w * 32) * LDT;
    unsigned short* lB2 = Bs2 + (w * 32) * LDT;

    floatx4 acc[MFR][4] = {};

    // compute one 32-K subtile from buffer (Ah,Bh)
    auto compute = [&](const unsigned short* Ah, const unsigned short* Bh) {
        short8 af[MFR], bfr[4];
#pragma unroll
        for (int mi = 0; mi < MFR; ++mi)
            af[mi] = *(const short8*)
                &Ah[(wm * (MFR * 16) + mi * 16 + c) * LDT + q * 8];
#pragma unroll
        for (int ni = 0; ni < 4; ++ni)
            bfr[ni] = *(const short8*)
                &Bh[(wn * 64 + ni * 16 + c) * LDT + q * 8];
#pragma unroll
        for (int mi = 0; mi < MFR; ++mi)
#pragma unroll
            for (int ni = 0; ni < 4; ++ni)
                acc[mi][ni] = MFMA32(af[mi], bfr[ni], acc[mi][ni]);
    };

    // stage one 32-K subtile (KEEP/2 G2L16 instructions)
    auto stage = [&](int nk, unsigned short* lA, unsigned short* lB) {
        G2L16(gA0 + nk, lA);
        if constexpr (MT == 128) G2L16(gA1 + nk, lA + 16 * LDT);
        G2L16(gB0 + nk, lB);
        G2L16(gB1 + nk, lB + 16 * LDT);
    };

    // one phase: stage subtile (knext -> lAn/lBn), compute buffer (Ac,Bc)
    auto phase = [&](int knext, unsigned short* lAn, unsigned short* lBn,
                     const unsigned short* Ac, const unsigned short* Bc) {
        __builtin_amdgcn_s_barrier();            // WAR: prev compute done
        stage(knext & (K - 1), lAn, lBn);        // wrap -> dead re-stage
        asm volatile("s_waitcnt vmcnt(%0)" :: "n"(KEEP) : "memory");
        __builtin_amdgcn_s_barrier();            // RAW: current buf visible
        __builtin_amdgcn_sched_barrier(0);
        compute(Ac, Bc);
    };

    // prologue: subtiles 0,1 -> buffers 0,1 (8 loads in flight)
    stage(0, lA0, lB0);
    stage(32, lA1, lB1);

    // phases p = 0..31 (subtile p in buffer p%3, stage p+2 into (p+2)%3)
    for (int g = 0; g < 10; ++g) {
        const int kb = g * 96;
        phase(kb +  64, lA2, lB2, As0, Bs0);  // p=3g
        phase(kb +  96, lA0, lB0, As1, Bs1);  // p=3g+1
        phase(kb + 128, lA1, lB1, As2, Bs2);  // p=3g+2 (g=9: dead-stage 0)
    }
    phase(1056, lA2, lB2, As0, Bs0);          // p=30: k=960, dead-stage
    phase(1088, lA0, lB0, As1, Bs1);          // p=31: k=992, dead-stage
    // drain dead prefetches: they must not be outstanding at s_endpgm (their
    // LDS destination is reallocated to the next block on this CU).
    asm volatile("s_waitcnt vmcnt(0)" ::: "memory");

#pragma unroll
    for (int ni = 0; ni < 4; ++ni) {
        const int col = n0 + wn * 64 + ni * 16 + c;
        const float bv = bias[col];
#pragma unroll
        for (int mi = 0; mi < MFR; ++mi)
#pragma unroll
            for (int r = 0; r < 4; ++r) {
                const int row = m0 + wm * (MFR * 16) + mi * 16 + q * 4 + r;
                const float v = (acc[mi][ni][r] + bv) * oscale;
                if constexpr (OMODE == 0) {
                    ((unsigned short*)Cv)[(size_t)row * N + col] = f2bf(v);
                } else if constexpr (OMODE == 1) {
                    const int b = row >> 11, s = row & 2047;
                    ((unsigned short*)Cv)[((size_t)(b * 1024 + col)) * SS + s] = f2bf(v);
                } else {
                    ((float*)Cv)[(size_t)row * N + col] = v;
                }
            }
    }
}

// grid (24 n-tiles, 32 m-tiles): same-W-tile blocks share an XCD (24 % 8 == 0).
__global__ __launch_bounds__(256) void k_gemm_qkv(
    const unsigned short* __restrict__ x, const unsigned short* __restrict__ y,
    const unsigned short* __restrict__ Wq, const float* __restrict__ bq,
    const unsigned short* __restrict__ Wk, const float* __restrict__ bk,
    const unsigned short* __restrict__ Wv, const float* __restrict__ bv,
    unsigned short* __restrict__ Q, unsigned short* __restrict__ Ko,
    unsigned short* __restrict__ Vt)
{
    __shared__ __align__(16) unsigned short As0[128 * 32], As1[128 * 32],
                                            As2[128 * 32];
    __shared__ __align__(16) unsigned short Bs0[128 * 32], Bs1[128 * 32],
                                            Bs2[128 * 32];
    const int m0 = blockIdx.y * 128;
    const int nt = blockIdx.x;
    const int g = nt >> 3;
    const int n0 = (nt & 7) * 128;
    if (g == 0) {
        gemm_body<128, 0>(x, Wq, bq, Q, QSCALE, m0, n0,
                          As0, As1, As2, Bs0, Bs1, Bs2);
    } else if (g == 1) {
        gemm_body<128, 0>(y, Wk, bk, Ko, 1.0f, m0, n0,
                          As0, As1, As2, Bs0, Bs1, Bs2);
    } else {
        gemm_body<128, 1>(y, Wv, bv, Vt, 1.0f, m0, n0,
                          As0, As1, As2, Bs0, Bs1, Bs2);
    }
}

// grid (8 n-tiles, 64 m-tiles), fp32 output.
__global__ __launch_bounds__(256) void k_gemm_out(
    const unsigned short* __restrict__ A, const unsigned short* __restrict__ W,
    const float* __restrict__ bias, float* __restrict__ C)
{
    __shared__ __align__(16) unsigned short As0[64 * 32], As1[64 * 32],
                                            As2[64 * 32];
    __shared__ __align__(16) unsigned short Bs0[128 * 32], Bs1[128 * 32],
                                            Bs2[128 * 32];
    gemm_body<64, 2>(A, W, bias, C, 1.0f, blockIdx.y * 64, blockIdx.x * 128,
                     As0, As1, As2, Bs0, Bs1, Bs2);
}

// ---------------------------------------------------------------------------
// Flash attention v7: VALU diet + unfenced scheduler.
// R2 post-mortem: occupancy 2x (R1) and load-latency hiding (R2) both flat at
// ~67-69us; time tracks total per-CU work -> a work pipe is the limiter, and
// VALUBusy (56%) is the highest. VALU hogs found by instruction accounting:
// (1) exp2f w/o fast-math expands to ~5-op libm fixup x32/wave-iter -> use
//     raw __builtin_amdgcn_exp2f (v_exp_f32; scores |s|<~8, 1-ulp safe);
// (2) s_setprio intrinsics are side-effecting scheduler FENCES: exp2/pack of
//     slice tt+1 could not interleave with PV MFMAs of slice tt -> removed,
//     and SM->PV fused per-tt at source so slice-level independence is
//     explicit in one basic block;
// (3) DS addresses recomputed every iter (buffer parity flips) -> unroll 2
//     makes parity compile-time so LICM hoists the 24 read addresses.
// R3 result: 67.4 -> 51.9us, VALUBusy 56 -> 38, MfmaUtil 35 -> 46. ~663 TF.
// Structure: 8 waves, split-K halves, dbuf LDS + reg prefetch, one
// barrier/iter, additive combine (no running max; pre-scaled exp2).
// ---------------------------------------------------------------------------
__global__ __launch_bounds__(512, 4) void k_attn(
    const unsigned short* __restrict__ Q, const unsigned short* __restrict__ K,
    const unsigned short* __restrict__ Vt, unsigned short* __restrict__ O)
{
    constexpr int LDK = 72;             // b128 frag reads: depth-8 uniform
    constexpr int TSZ = 64 * LDK + 64 * 64;  // ushorts per K+V buffer
    __shared__ __align__(16) unsigned short smem[2 * 2 * TSZ];  // 69632 B
    float* Ob = (float*)smem;           // combine reuse: [128][66] fp32

    const int bh = blockIdx.x, qt = blockIdx.y;
    const int b = bh >> 4, h = bh & 15;
    const int t = threadIdx.x, w = t >> 6;
    const int ws = w >> 2;   // key half: 0 -> keys [0,1024), 1 -> [1024,2048)
    const int wq = w & 3;    // Q-row group within the 128-row tile
    const int lane = t & 63, q = lane >> 4, c = lane & 15;

    unsigned short* Sb = smem + ws * (2 * TSZ);  // this half's buffer pair

    // Q B-frags (B[k=d=q*8+j][n=qrow=c]), two 16-row groups per wave.
    short8 qb[2][2];
#pragma unroll
    for (int g = 0; g < 2; ++g) {
        const size_t qoff =
            (size_t)(b * SS + qt * 128 + wq * 32 + g * 16 + c) * EE + h * DD + q * 8;
        qb[g][0] = *(const short8*)(Q + qoff);
        qb[g][1] = *(const short8*)(Q + qoff + 32);
    }

    floatx4 o[2][4] = {};
    floatx4 lacc[2] = {};
    const shortx4 ones = {(short)0x3F80, (short)0x3F80, (short)0x3F80, (short)0x3F80};

    // staging: each 256-thread half stages its own K/V tile (64 keys x 64 d).
    const int ts = t & 255;
    const int sr = ts >> 2, sp = (ts & 3) * 16;  // staging row / col chunk
    const int vkey = (sr & 15) << 2;
    const unsigned short* Kg =
        K + (size_t)(b * SS + ws * 1024 + sr) * EE + h * DD + sp;
    const unsigned short* Vg =
        Vt + ((size_t)bh * DD + sr) * SS + ws * 1024 + sp;

    // prologue: tile 0 -> buf 0
    {
        const ushort8* gk = (const ushort8*)Kg;
        ushort8 k0 = gk[0], k1 = gk[1];
        const ushort8* gv = (const ushort8*)Vg;
        ushort8 v0 = gv[0], v1 = gv[1];
        unsigned short* Ks = Sb;
        unsigned short* Vs = Sb + 64 * LDK;
        *(ushort8*)&Ks[sr * LDK + sp] = k0;
        *(ushort8*)&Ks[sr * LDK + sp + 8] = k1;
        *(ush4*)&Vs[sr * 64 + ((sp +  0) ^ vkey)] =
            __builtin_shufflevector(v0, v0, 0, 1, 2, 3);
        *(ush4*)&Vs[sr * 64 + ((sp +  4) ^ vkey)] =
            __builtin_shufflevector(v0, v0, 4, 5, 6, 7);
        *(ush4*)&Vs[sr * 64 + ((sp +  8) ^ vkey)] =
            __builtin_shufflevector(v1, v1, 0, 1, 2, 3);
        *(ush4*)&Vs[sr * 64 + ((sp + 12) ^ vkey)] =
            __builtin_shufflevector(v1, v1, 4, 5, 6, 7);
    }

#pragma unroll 2
    for (int it = 0; it < 16; ++it) {
        const unsigned short* Ks = Sb + (it & 1) * TSZ;
        const unsigned short* Vs = Ks + 64 * LDK;
        __syncthreads();  // buf[it&1] writes visible; prev reads complete

        // issue next-tile loads (wrap at tail: it=15 re-reads tile 0, whose
        // write lands in buf0 which is never read again -- keeps the loads
        // unconditional so the scheduler can't sink them past the compute).
        const int nit = (it + 1) & 15;
        ushort8 pk0, pk1, pv0, pv1;
        {
            const ushort8* gk = (const ushort8*)(Kg + (size_t)nit * 64 * EE);
            pk0 = gk[0]; pk1 = gk[1];
            const ushort8* gv = (const ushort8*)(Vg + nit * 64);
            pv0 = gv[0]; pv1 = gv[1];
        }

        // Fused per-K-slice: S^T (A = K rows sk=tt*16+c, B = Q rows) -> exp2
        // -> pack -> PV + lsum. Lane: P[sk=tt*16+q*4+r][qrow=c]. Slices are
        // independent (o-accum distance = 10 MFMA16s) -> scheduler overlaps
        // slice tt+1's trans/VALU with slice tt's MFMA16s.
#pragma unroll
        for (int tt = 0; tt < 4; ++tt) {
            const short8 ka0 = *(const short8*)&Ks[(tt * 16 + c) * LDK + q * 8];
            const short8 ka1 = *(const short8*)&Ks[(tt * 16 + c) * LDK + 32 + q * 8];
            shortx4 pa[2];
#pragma unroll
            for (int g = 0; g < 2; ++g) {
                floatx4 s = {0.f, 0.f, 0.f, 0.f};
                s = MFMA32(ka0, qb[g][0], s);
                s = MFMA32(ka1, qb[g][1], s);
                union { unsigned int u[2]; shortx4 v; } pk;
                pk.u[0] = pkbf(__builtin_amdgcn_exp2f(s[0]),
                               __builtin_amdgcn_exp2f(s[1]));
                pk.u[1] = pkbf(__builtin_amdgcn_exp2f(s[2]),
                               __builtin_amdgcn_exp2f(s[3]));
                pa[g] = pk.v;
            }
            // O += P*V: A[m=qrow=c][k=q*4+j]; B[k][n=dv=c] from swizzled Vs.
#pragma unroll
            for (int nd = 0; nd < 4; ++nd) {
                const shortx4 vb = *(const shortx4*)
                    &Vs[(nd * 16 + c) * 64 + (((tt * 4 + q) ^ c) << 2)];
                o[0][nd] = MFMA16(pa[0], vb, o[0][nd]);
                o[1][nd] = MFMA16(pa[1], vb, o[1][nd]);
            }
            lacc[0] = MFMA16(pa[0], ones, lacc[0]);
            lacc[1] = MFMA16(pa[1], ones, lacc[1]);
        }

        // write prefetched tile -> other buffer (vmcnt drain hidden by compute)
        {
            unsigned short* Kn = Sb + ((it + 1) & 1) * TSZ;
            unsigned short* Vn = Kn + 64 * LDK;
            *(ushort8*)&Kn[sr * LDK + sp] = pk0;
            *(ushort8*)&Kn[sr * LDK + sp + 8] = pk1;
            *(ush4*)&Vn[sr * 64 + ((sp +  0) ^ vkey)] =
                __builtin_shufflevector(pv0, pv0, 0, 1, 2, 3);
            *(ush4*)&Vn[sr * 64 + ((sp +  4) ^ vkey)] =
                __builtin_shufflevector(pv0, pv0, 4, 5, 6, 7);
            *(ush4*)&Vn[sr * 64 + ((sp +  8) ^ vkey)] =
                __builtin_shufflevector(pv1, pv1, 0, 1, 2, 3);
            *(ush4*)&Vn[sr * 64 + ((sp + 12) ^ vkey)] =
                __builtin_shufflevector(pv1, pv1, 4, 5, 6, 7);
        }
    }

    // ---- combine the two key halves (additive: no running max) ----
    __syncthreads();  // all staging traffic done; safe to reuse smem as Ob
    if (ws == 1) {
#pragma unroll
        for (int g = 0; g < 2; ++g) {
#pragma unroll
            for (int nd = 0; nd < 4; ++nd)
#pragma unroll
                for (int r = 0; r < 4; ++r)
                    Ob[(wq * 32 + g * 16 + q * 4 + r) * 66 + nd * 16 + c] =
                        o[g][nd][r];
            if (c == 0) {
#pragma unroll
                for (int r = 0; r < 4; ++r)
                    Ob[(wq * 32 + g * 16 + q * 4 + r) * 66 + 64] = lacc[g][r];
            }
        }
    }
    __syncthreads();
    if (ws == 0) {
#pragma unroll
        for (int g = 0; g < 2; ++g) {
            float linv[4];
#pragma unroll
            for (int r = 0; r < 4; ++r) {
                const int rr = wq * 32 + g * 16 + q * 4 + r;
#pragma unroll
                for (int nd = 0; nd < 4; ++nd)
                    o[g][nd][r] += Ob[rr * 66 + nd * 16 + c];
                linv[r] = __builtin_amdgcn_rcpf(lacc[g][r] + Ob[rr * 66 + 64]);
            }
            const int orow = b * SS + qt * 128 + wq * 32 + g * 16;
#pragma unroll
            for (int nd = 0; nd < 4; ++nd)
#pragma unroll
                for (int r = 0; r < 4; ++r)
                    O[(size_t)(orow + q * 4 + r) * EE + h * DD + nd * 16 + c] =
                        f2bf(o[g][nd][r] * linv[r]);
        }
    }
}

// ---------------------------------------------------------------------------
extern "C" void kernel_launch(void* const* d_in, const int* in_sizes, int n_in,
                              void* d_out, int out_size, void* d_ws, size_t ws_size,
                              hipStream_t stream)
{
    const float* x  = (const float*)d_in[0];
    const float* y  = (const float*)d_in[1];
    // d_in[2] = mask (int32) — faithfully ignored, as in the reference
    const float* Wq = (const float*)d_in[3];
    const float* bq = (const float*)d_in[4];
    const float* Wk = (const float*)d_in[5];
    const float* bk = (const float*)d_in[6];
    const float* Wv = (const float*)d_in[7];
    const float* bv = (const float*)d_in[8];
    const float* Wo = (const float*)d_in[9];
    const float* bo = (const float*)d_in[10];
    float* out = (float*)d_out;

    char* ws = (char*)d_ws;
    const size_t SZ = (size_t)BB * SS * EE * sizeof(unsigned short);  // 8 MiB
    const size_t WZ = (size_t)EE * EE * sizeof(unsigned short);       // 2 MiB
    unsigned short* xb  = (unsigned short*)(ws);
    unsigned short* yb  = (unsigned short*)(ws + SZ);
    unsigned short* Wqb = (unsigned short*)(ws + 2 * SZ);
    unsigned short* Wkb = (unsigned short*)(ws + 2 * SZ + WZ);
    unsigned short* Wvb = (unsigned short*)(ws + 2 * SZ + 2 * WZ);
    unsigned short* Wob = (unsigned short*)(ws + 2 * SZ + 3 * WZ);
    unsigned short* Qw  = (unsigned short*)(ws + 2 * SZ + 4 * WZ);
    unsigned short* Kw  = (unsigned short*)(ws + 3 * SZ + 4 * WZ);
    unsigned short* Vtw = (unsigned short*)(ws + 4 * SZ + 4 * WZ);
    unsigned short* Aw  = (unsigned short*)(ws + 5 * SZ + 4 * WZ);
    (void)ws_size; (void)in_sizes; (void)n_in; (void)out_size;

    k_cvt<<<dim3(1024, 6), 256, 0, stream>>>(x, xb, y, yb, Wq, Wqb, Wk, Wkb,
                                             Wv, Wvb, Wo, Wob);
    k_gemm_qkv<<<dim3(24, 32), 256, 0, stream>>>(xb, yb, Wqb, bq, Wkb, bk, Wvb, bv,
                                                 Qw, Kw, Vtw);
    k_attn<<<dim3(32, 16), 512, 0, stream>>>(Qw, Kw, Vtw, Aw);
    k_gemm_out<<<dim3(8, 64), 256, 0, stream>>>(Aw, Wob, bo, out);
}